// Round 4
// baseline (10.802 us; speedup 1.0000x reference)
//
#include <hip/hip_runtime.h>

// CNN2: reference collapses because Y = W @ ones(30,T) is rank-1 (every column
// == rowsum(W) = r). Per-lag trace normalization cancels the lag-dependent
// overlap count, so S_mean is lag-independent:
//   Sm = r r^T / ||r||^2,  Sv = 0  (fp noise ~1e-17)
//   Gm = 0.5*(Sm+1), Gv = 0.5 (constant channel), pad = 0
// Conv1 valid-tap contribution: (0.5*s_inv*r_iy*r_ix + 0.5)*w0 + 0.5*w1.
// R3: W never staged (wave 0 rowsums straight from global, 2 lanes/row,
// overlapped with weight staging by waves 1-8); conv2+pool2+linear fully
// in-register in wave 0 (no c2o buffer, no barrier after conv2).
// 2 barriers total, ~3.7 KB LDS, 3 phases.

#define NN 30

__global__ __launch_bounds__(576) void cnn2_fused(
    const float* __restrict__ Wg,
    const float4* __restrict__ c1w4, const float* __restrict__ c1b,
    const float4* __restrict__ c2w4, const float* __restrict__ c2b,
    const float4* __restrict__ ow4,  const float* __restrict__ ob,
    float* __restrict__ out)
{
    __shared__ __align__(16) float s_c1w[256];
    __shared__ __align__(16) float s_c2w[512];
    __shared__ __align__(16) float s_ow[32];
    __shared__ float s_c1b[8], s_c2b[16], s_ob[2];
    __shared__ float r[NN];
    __shared__ float s_hsinv;                   // 0.5 / ||r||^2
    __shared__ float p1[72];                    // pool1: oc*9 + py*3 + px

    const int tid = threadIdx.x;

    // ---- Phase A: wave 0 computes r + hsinv from global W; waves 1-8 stage
    //      all weights. One barrier covers both. ----
    if (tid < 64) {
        const int half = tid >> 5;              // 0 or 1 (which 15-col half)
        const int row  = tid & 31;              // rows 0..29 valid
        float s = 0.f;
        if (row < NN) {
            const float* wr = Wg + row * NN + half * 15;
            #pragma unroll
            for (int j = 0; j < 15; ++j) s += wr[j];
        }
        s += __shfl_xor(s, 32);                 // full row sum, both halves
        if (half == 0 && row < NN) r[row] = s;
        float v = s * s;                        // each row counted twice
        #pragma unroll
        for (int m = 32; m; m >>= 1) v += __shfl_xor(v, m);  // = 2*ssq
        if (tid == 0) s_hsinv = 1.0f / v;       // = 0.5/ssq
    } else if (tid < 128) {
        ((float4*)s_c1w)[tid - 64] = c1w4[tid - 64];
    } else if (tid < 256) {
        ((float4*)s_c2w)[tid - 128] = c2w4[tid - 128];
    } else if (tid < 264) {
        ((float4*)s_ow)[tid - 256] = ow4[tid - 256];
    } else if (tid < 272) {
        s_c1b[tid - 264] = c1b[tid - 264];
    } else if (tid < 288) {
        s_c2b[tid - 272] = c2b[tid - 272];
    } else if (tid < 290) {
        s_ob[tid - 288] = ob[tid - 288];
    }
    __syncthreads();                                            // b1

    // ---- Phase B: conv1 + leaky + pool1, fused. 8 lanes per pool window.
    // Only the 24x24 region feeds the 3x3 pool; taps reach iy/ix -1..25, so
    // only the >= 0 edge can clip.
    {
        const int wdw = tid >> 3;           // 0..71
        const int row = tid & 7;
        const int oc  = wdw / 9;
        const int rm  = wdw % 9;
        const int py  = rm / 3, px = rm % 3;
        const int oy  = py * 8 + row;
        const float hsinv = s_hsinv;

        float ry[4];
        #pragma unroll
        for (int ky = 0; ky < 4; ++ky) {
            int iy = oy + ky - 1;
            ry[ky] = (iy >= 0) ? r[iy] : 0.f;
        }
        float rv[11];
        #pragma unroll
        for (int j = 0; j < 11; ++j) {
            int ix = px * 8 - 1 + j;
            rv[j] = (ix >= 0) ? r[ix] : 0.f;
        }
        float wry[16];
        float sw_full = 0.f, sw_col0 = 0.f;
        #pragma unroll
        for (int ky = 0; ky < 4; ++ky) {
            const bool vld = (oy + ky - 1) >= 0;
            #pragma unroll
            for (int kx = 0; kx < 4; ++kx) {
                float w0 = s_c1w[(oc * 2 + 0) * 16 + ky * 4 + kx];
                float w1 = s_c1w[(oc * 2 + 1) * 16 + ky * 4 + kx];
                wry[ky * 4 + kx] = ry[ky] * w0;
                if (vld) {
                    float sw = w0 + w1;
                    sw_full += sw;
                    if (kx == 0) sw_col0 += sw;
                }
            }
        }
        const float bias = s_c1b[oc];
        float m = -INFINITY;
        #pragma unroll
        for (int q = 0; q < 8; ++q) {
            float acc = 0.f;
            #pragma unroll
            for (int ky = 0; ky < 4; ++ky)
                #pragma unroll
                for (int kx = 0; kx < 4; ++kx)
                    acc += rv[q + kx] * wry[ky * 4 + kx];
            float aw  = (px == 0 && q == 0) ? (sw_full - sw_col0) : sw_full;
            float val = bias + hsinv * acc + 0.5f * aw;
            val = val >= 0.f ? val : 0.2f * val;
            m = fmaxf(m, val);
        }
        m = fmaxf(m, __shfl_xor(m, 1));
        m = fmaxf(m, __shfl_xor(m, 2));
        m = fmaxf(m, __shfl_xor(m, 4));
        if (row == 0) p1[wdw] = m;
    }
    __syncthreads();                                            // b2

    // ---- Phase C (wave 0, register-resident): conv2 + leaky + pool2 +
    //      linear, no further barriers. Lane = (oc, oy); 4 ox outputs. ----
    if (tid < 64) {
        const int oc = tid >> 2;            // 0..15
        const int oy = tid & 3;             // 0..3
        float m = -INFINITY;
        #pragma unroll
        for (int ox = 0; ox < 4; ++ox) {
            float acc = s_c2b[oc];
            #pragma unroll
            for (int ky = 0; ky < 2; ++ky) {
                const int iy = oy + ky - 1;
                if (iy < 0 || iy > 2) continue;
                #pragma unroll
                for (int kx = 0; kx < 2; ++kx) {
                    const int ix = ox + kx - 1;
                    if (ix < 0 || ix > 2) continue;
                    #pragma unroll
                    for (int ic = 0; ic < 8; ++ic)
                        acc += p1[ic * 9 + iy * 3 + ix] *
                               s_c2w[((oc * 8 + ic) * 2 + ky) * 2 + kx];
                }
            }
            acc = acc >= 0.f ? acc : 0.2f * acc;
            m = fmaxf(m, acc);
        }
        m = fmaxf(m, __shfl_xor(m, 1));
        m = fmaxf(m, __shfl_xor(m, 2));          // h[oc] in lanes 4oc..4oc+3
        float h = __shfl(m, (tid & 15) << 2);    // gather h[tid&15]
        float part = (tid < 32) ? h * s_ow[tid] : 0.f;
        part += __shfl_xor(part, 8);
        part += __shfl_xor(part, 4);
        part += __shfl_xor(part, 2);
        part += __shfl_xor(part, 1);
        if (tid == 0)  out[0] = part + s_ob[0];
        if (tid == 16) out[1] = part + s_ob[1];
    }
}

extern "C" void kernel_launch(void* const* d_in, const int* in_sizes, int n_in,
                              void* d_out, int out_size, void* d_ws, size_t ws_size,
                              hipStream_t stream) {
    // d_in order: 0=x(unused), 1=W, 2=conv1_w, 3=conv1_b, 4=conv2_w,
    // 5=conv2_b, 6=out_w, 7=out_b, 8=col(unused — cancels in trace norm)
    const float*  Wg   = (const float*)d_in[1];
    const float4* c1w4 = (const float4*)d_in[2];
    const float*  c1b  = (const float*)d_in[3];
    const float4* c2w4 = (const float4*)d_in[4];
    const float*  c2b  = (const float*)d_in[5];
    const float4* ow4  = (const float4*)d_in[6];
    const float*  ob   = (const float*)d_in[7];
    float* out = (float*)d_out;

    cnn2_fused<<<1, 576, 0, stream>>>(Wg, c1w4, c1b, c2w4, c2b, ow4, ob, out);
}

// Round 5
// 10.600 us; speedup vs baseline: 1.0190x; 1.0190x over previous
//
#include <hip/hip_runtime.h>

// CNN2: reference collapses because Y = W @ ones(30,T) is rank-1 (every column
// == rowsum(W) = r). Per-lag trace normalization cancels the lag-dependent
// overlap count, so S_mean is lag-independent:
//   Sm = r r^T / ||r||^2,  Sv = 0  (fp noise ~1e-17)
//   Gm = 0.5*(Sm+1), Gv = 0.5 (constant channel), pad = 0
// Conv1 valid-tap contribution: (0.5*s_inv*r_iy*r_ix + 0.5)*w0 + 0.5*w1.
// R4: A/B decomposition of R3's regression — restore R2's float4 burst
// staging of W (225 parallel lanes, max MLP on the critical chain), keep
// R3's fused conv2+pool2+linear wave-0 tail (one barrier + 1KB LDS fewer
// than R2). 3 barriers, ~8 KB LDS.

#define NN 30

__global__ __launch_bounds__(576) void cnn2_fused(
    const float4* __restrict__ W4,
    const float4* __restrict__ c1w4, const float* __restrict__ c1b,
    const float4* __restrict__ c2w4, const float* __restrict__ c2b,
    const float4* __restrict__ ow4,  const float* __restrict__ ob,
    float* __restrict__ out)
{
    __shared__ __align__(16) float w[900];      // staged W
    __shared__ __align__(16) float s_c1w[256];
    __shared__ __align__(16) float s_c2w[512];
    __shared__ __align__(16) float s_ow[32];
    __shared__ float s_c1b[8], s_c2b[16], s_ob[2];
    __shared__ float r[NN];
    __shared__ float s_hsinv;                   // 0.5 / ||r||^2
    __shared__ float p1[72];                    // pool1: oc*9 + py*3 + px

    const int tid = threadIdx.x;

    // ---- Phase A: every global load, vectorized, one parallel burst ----
    if (tid < 225)      ((float4*)w)[tid]           = W4[tid];
    else if (tid < 289) ((float4*)s_c1w)[tid - 225] = c1w4[tid - 225];
    else if (tid < 417) ((float4*)s_c2w)[tid - 289] = c2w4[tid - 289];
    else if (tid < 425) ((float4*)s_ow)[tid - 417]  = ow4[tid - 417];
    else if (tid < 433) s_c1b[tid - 425] = c1b[tid - 425];
    else if (tid < 449) s_c2b[tid - 433] = c2b[tid - 433];
    else if (tid < 451) s_ob[tid - 449]  = ob[tid - 449];
    __syncthreads();                                            // b1

    // ---- Phase B (wave 0): rowsum + ssq, register shuffles ----
    if (tid < 64) {
        float s = 0.f;
        if (tid < NN) {
            #pragma unroll
            for (int j = 0; j < NN; ++j) s += w[tid * NN + j];
            r[tid] = s;
        }
        float v = s * s;                    // lanes >= 30 contribute 0
        #pragma unroll
        for (int m = 32; m; m >>= 1) v += __shfl_xor(v, m);
        if (tid == 0) s_hsinv = 0.5f / v;
    }
    __syncthreads();                                            // b2

    // ---- Phase C: conv1 + leaky + pool1, fused. 8 lanes per pool window.
    // Only the 24x24 region feeds the 3x3 pool; taps reach iy/ix -1..25, so
    // only the >= 0 edge can clip.
    {
        const int wdw = tid >> 3;           // 0..71
        const int row = tid & 7;
        const int oc  = wdw / 9;
        const int rm  = wdw % 9;
        const int py  = rm / 3, px = rm % 3;
        const int oy  = py * 8 + row;
        const float hsinv = s_hsinv;

        float ry[4];
        #pragma unroll
        for (int ky = 0; ky < 4; ++ky) {
            int iy = oy + ky - 1;
            ry[ky] = (iy >= 0) ? r[iy] : 0.f;
        }
        float rv[11];
        #pragma unroll
        for (int j = 0; j < 11; ++j) {
            int ix = px * 8 - 1 + j;
            rv[j] = (ix >= 0) ? r[ix] : 0.f;
        }
        float wry[16];
        float sw_full = 0.f, sw_col0 = 0.f;
        #pragma unroll
        for (int ky = 0; ky < 4; ++ky) {
            const bool vld = (oy + ky - 1) >= 0;
            #pragma unroll
            for (int kx = 0; kx < 4; ++kx) {
                float w0 = s_c1w[(oc * 2 + 0) * 16 + ky * 4 + kx];
                float w1 = s_c1w[(oc * 2 + 1) * 16 + ky * 4 + kx];
                wry[ky * 4 + kx] = ry[ky] * w0;
                if (vld) {
                    float sw = w0 + w1;
                    sw_full += sw;
                    if (kx == 0) sw_col0 += sw;
                }
            }
        }
        const float bias = s_c1b[oc];
        float m = -INFINITY;
        #pragma unroll
        for (int q = 0; q < 8; ++q) {
            float acc = 0.f;
            #pragma unroll
            for (int ky = 0; ky < 4; ++ky)
                #pragma unroll
                for (int kx = 0; kx < 4; ++kx)
                    acc += rv[q + kx] * wry[ky * 4 + kx];
            float aw  = (px == 0 && q == 0) ? (sw_full - sw_col0) : sw_full;
            float val = bias + hsinv * acc + 0.5f * aw;
            val = val >= 0.f ? val : 0.2f * val;
            m = fmaxf(m, val);
        }
        m = fmaxf(m, __shfl_xor(m, 1));
        m = fmaxf(m, __shfl_xor(m, 2));
        m = fmaxf(m, __shfl_xor(m, 4));
        if (row == 0) p1[wdw] = m;
    }
    __syncthreads();                                            // b3

    // ---- Phase D (wave 0, register-resident): conv2 + leaky + pool2 +
    //      linear, no further barriers. Lane = (oc, oy); 4 ox outputs. ----
    if (tid < 64) {
        const int oc = tid >> 2;            // 0..15
        const int oy = tid & 3;             // 0..3
        float m = -INFINITY;
        #pragma unroll
        for (int ox = 0; ox < 4; ++ox) {
            float acc = s_c2b[oc];
            #pragma unroll
            for (int ky = 0; ky < 2; ++ky) {
                const int iy = oy + ky - 1;
                if (iy < 0 || iy > 2) continue;
                #pragma unroll
                for (int kx = 0; kx < 2; ++kx) {
                    const int ix = ox + kx - 1;
                    if (ix < 0 || ix > 2) continue;
                    #pragma unroll
                    for (int ic = 0; ic < 8; ++ic)
                        acc += p1[ic * 9 + iy * 3 + ix] *
                               s_c2w[((oc * 8 + ic) * 2 + ky) * 2 + kx];
                }
            }
            acc = acc >= 0.f ? acc : 0.2f * acc;
            m = fmaxf(m, acc);
        }
        m = fmaxf(m, __shfl_xor(m, 1));
        m = fmaxf(m, __shfl_xor(m, 2));          // h[oc] in lanes 4oc..4oc+3
        float h = __shfl(m, (tid & 15) << 2);    // gather h[tid&15]
        float part = (tid < 32) ? h * s_ow[tid] : 0.f;
        part += __shfl_xor(part, 8);
        part += __shfl_xor(part, 4);
        part += __shfl_xor(part, 2);
        part += __shfl_xor(part, 1);
        if (tid == 0)  out[0] = part + s_ob[0];
        if (tid == 16) out[1] = part + s_ob[1];
    }
}

extern "C" void kernel_launch(void* const* d_in, const int* in_sizes, int n_in,
                              void* d_out, int out_size, void* d_ws, size_t ws_size,
                              hipStream_t stream) {
    // d_in order: 0=x(unused), 1=W, 2=conv1_w, 3=conv1_b, 4=conv2_w,
    // 5=conv2_b, 6=out_w, 7=out_b, 8=col(unused — cancels in trace norm)
    const float4* W4   = (const float4*)d_in[1];
    const float4* c1w4 = (const float4*)d_in[2];
    const float*  c1b  = (const float*)d_in[3];
    const float4* c2w4 = (const float4*)d_in[4];
    const float*  c2b  = (const float*)d_in[5];
    const float4* ow4  = (const float4*)d_in[6];
    const float*  ob   = (const float*)d_in[7];
    float* out = (float*)d_out;

    cnn2_fused<<<1, 576, 0, stream>>>(W4, c1w4, c1b, c2w4, c2b, ow4, ob, out);
}